// Round 12
// baseline (194.805 us; speedup 1.0000x reference)
//
#include <hip/hip_runtime.h>

// PointPillars scatter: canvas[b, c, y, x] = feat[n, c] where coords[n] = (b, _, y, x)
// R12: FILL-SHAPED linear output sweep + 2-deep software pipeline.
//   K1: map[:] = -1
//   K2: map[b*NY*NX + y*NX + x] = n          (collision-free per problem spec)
//   K3: grid-stride over 16B output chunks in LINEAR order (the exact pattern
//       the 6.9 TB/s fill kernel uses). Pipeline: iter j loads map[j+2S],
//       gathers for j+S, stores j -> map/gather latency never on the store
//       path (R5 failed this shape only because its chain was unpipelined).
//       Gathers use clamp+cndmask (no divergent loads). nt stores (R11 proved
//       nt > plain for our kernels), nt map loads (single-use).

#define NXD 400
#define NYD 400
#define CCH 64
#define NXY (NXD * NYD)   // 160000 cells/sample, divisible by 4

typedef float fvec4 __attribute__((ext_vector_type(4)));
typedef int   ivec4 __attribute__((ext_vector_type(4)));

__global__ void pps_init_map(ivec4* __restrict__ map4, int total4) {
    int i = blockIdx.x * blockDim.x + threadIdx.x;
    int stride = gridDim.x * blockDim.x;
    ivec4 neg1 = {-1, -1, -1, -1};
    for (; i < total4; i += stride)
        __builtin_nontemporal_store(neg1, map4 + i);
}

__global__ void pps_build_map(const int* __restrict__ coords, int* __restrict__ map, int n) {
    int i = blockIdx.x * blockDim.x + threadIdx.x;
    if (i >= n) return;
    ivec4 c4 = *(const ivec4*)(coords + i * 4);   // (b, _, y, x)
    map[c4.x * NXY + c4.z * NXD + c4.w] = i;
}

// chunk j (16B of output) -> map index of its 4 cells, channel c
__device__ __forceinline__ void chunk_info(int j, int& mi, int& c) {
    int o4 = j * 4;                                  // float index
    unsigned bc = (unsigned)o4 / (unsigned)NXY;      // magic-mul div
    int s = o4 - (int)bc * NXY;                      // cell within plane
    c  = (int)(bc & 63u);
    mi = (int)(bc >> 6) * NXY + s;
}

__device__ __forceinline__ fvec4 gather4(const float* __restrict__ feat, ivec4 m, int c) {
    // clamp to row 0 (broadcast line), unconditional loads, cndmask select
    float a = feat[(size_t)(m.x >= 0 ? m.x : 0) * CCH + c];
    float b = feat[(size_t)(m.y >= 0 ? m.y : 0) * CCH + c];
    float d = feat[(size_t)(m.z >= 0 ? m.z : 0) * CCH + c];
    float e = feat[(size_t)(m.w >= 0 ? m.w : 0) * CCH + c];
    fvec4 v;
    v.x = m.x >= 0 ? a : 0.0f;
    v.y = m.y >= 0 ? b : 0.0f;
    v.z = m.z >= 0 ? d : 0.0f;
    v.w = m.w >= 0 ? e : 0.0f;
    return v;
}

__global__ __launch_bounds__(256) void pps_linear(const float* __restrict__ feat,
                                                  const int* __restrict__ map,
                                                  float* __restrict__ out,
                                                  int nchunks) {
    const int tid    = blockIdx.x * blockDim.x + threadIdx.x;
    const int stride = gridDim.x * blockDim.x;
    if (tid >= nchunks) return;

    fvec4* out4 = (fvec4*)out;

    // ---- prologue: map[j0], map[j1]; gathers for j0 ----
    int mi0, c0;
    chunk_info(tid, mi0, c0);
    ivec4 m_cur = __builtin_nontemporal_load((const ivec4*)(map + mi0));

    int j1 = tid + stride;
    int jl1 = (j1 < nchunks) ? j1 : tid;             // clamped (value unused if OOB)
    int mi1, c1p;
    chunk_info(jl1, mi1, c1p);
    ivec4 m_nxt = __builtin_nontemporal_load((const ivec4*)(map + mi1));

    fvec4 g_cur = gather4(feat, m_cur, c0);

    // ---- steady state: load map[j+2S] | gather[j+S] | store[j] ----
    for (int j = tid; j < nchunks; j += stride) {
        int j2  = j + 2 * stride;
        int jl2 = (j2 < nchunks) ? j2 : j;
        int mi2, c2;
        chunk_info(jl2, mi2, c2);
        ivec4 m_new = __builtin_nontemporal_load((const ivec4*)(map + mi2));

        int jn  = j + stride;
        int jln = (jn < nchunks) ? jn : j;
        int min_, cn;
        chunk_info(jln, min_, cn);
        (void)min_;
        fvec4 g_next = gather4(feat, m_nxt, cn);

        __builtin_nontemporal_store(g_cur, out4 + j);

        g_cur = g_next;
        m_nxt = m_new;
    }
}

extern "C" void kernel_launch(void* const* d_in, const int* in_sizes, int n_in,
                              void* d_out, int out_size, void* d_ws, size_t ws_size,
                              hipStream_t stream) {
    const float* feat  = (const float*)d_in[0];   // [N, 64] fp32
    const int* coords  = (const int*)d_in[1];     // [N, 4] int32 (b, _, y, x)
    float* out         = (float*)d_out;           // [B, 64, NY, NX] fp32

    const int n_pillars = in_sizes[1] / 4;
    const int batch     = out_size / (CCH * NXY);
    const int total_pos = batch * NXY;            // 1.28M cells

    int* map = (int*)d_ws;                        // batch*NXY*4 = 5.12 MB

    // K1: reset map every call (d_ws not re-poisoned between replays)
    pps_init_map<<<1024, 256, 0, stream>>>((ivec4*)map, total_pos / 4);

    // K2: scatter pillar indices into the map
    pps_build_map<<<(n_pillars + 255) / 256, 256, 0, stream>>>(coords, map, n_pillars);

    // K3: linear fill-shaped sweep, 2048 blocks x 256 (32 waves/CU)
    {
        int nchunks = out_size / 4;               // 20.48M 16B chunks
        pps_linear<<<2048, 256, 0, stream>>>(feat, map, out, nchunks);
    }
}

// Round 13
// 107.120 us; speedup vs baseline: 1.8186x; 1.8186x over previous
//
#include <hip/hip_runtime.h>

// PointPillars scatter: canvas[b, c, y, x] = feat[n, c] where coords[n] = (b, _, y, x)
// R13: contiguous per-block write streams (fill's shape) + full occupancy +
//      2-deep pipelined reads (R10's discipline). The untested matrix cell:
//      R8 had these streams but same-iteration gathers (read latency on the
//      store path); R10 had pipelined reads but strided-plane stores.
//   K1: map[:] = -1
//   K2: map[b*NY*NX + y*NX + x] = n          (collision-free per problem spec)
//   K3: block=(b,c,quarter): 2048 blocks, 32 waves/CU; each block writes ONE
//       contiguous 160KB run. b = bid % batch -> sample pinned per XCD
//       (map slice 640KB + feat slice ~3MB L2-resident, map re-reads on-XCD).
//       Pipeline: load map[j+2S] | gather[j+S] (clamp+cndmask) | nt-store j.

#define NXD 400
#define NYD 400
#define CCH 64
#define NXY (NXD * NYD)      // 160000 cells/sample
#define QCELLS 40000         // cells per quarter-plane
#define QCHUNK (QCELLS / 4)  // 10000 16B chunks per quarter-plane

typedef float fvec4 __attribute__((ext_vector_type(4)));
typedef int   ivec4 __attribute__((ext_vector_type(4)));

__global__ void pps_init_map(ivec4* __restrict__ map4, int total4) {
    int i = blockIdx.x * blockDim.x + threadIdx.x;
    int stride = gridDim.x * blockDim.x;
    ivec4 neg1 = {-1, -1, -1, -1};
    for (; i < total4; i += stride)
        __builtin_nontemporal_store(neg1, map4 + i);
}

__global__ void pps_build_map(const int* __restrict__ coords, int* __restrict__ map, int n) {
    int i = blockIdx.x * blockDim.x + threadIdx.x;
    if (i >= n) return;
    ivec4 c4 = *(const ivec4*)(coords + i * 4);   // (b, _, y, x)
    map[c4.x * NXY + c4.z * NXD + c4.w] = i;
}

__device__ __forceinline__ fvec4 gatherc(const float* __restrict__ feat, ivec4 m, int c) {
    // clamp to row 0 (broadcast line), unconditional loads, cndmask select
    float a = feat[(size_t)(m.x >= 0 ? m.x : 0) * CCH + c];
    float b = feat[(size_t)(m.y >= 0 ? m.y : 0) * CCH + c];
    float d = feat[(size_t)(m.z >= 0 ? m.z : 0) * CCH + c];
    float e = feat[(size_t)(m.w >= 0 ? m.w : 0) * CCH + c];
    fvec4 v;
    v.x = m.x >= 0 ? a : 0.0f;
    v.y = m.y >= 0 ? b : 0.0f;
    v.z = m.z >= 0 ? d : 0.0f;
    v.w = m.w >= 0 ? e : 0.0f;
    return v;
}

__global__ __launch_bounds__(256) void pps_stream(const float* __restrict__ feat,
                                                  const int* __restrict__ map,
                                                  float* __restrict__ out,
                                                  int batch) {
    // bid = (c * 4 + q) * batch + b  -> consecutive blocks round-robin XCDs
    int bid = blockIdx.x;
    int b   = bid % batch;
    int tmp = bid / batch;
    int q   = tmp & 3;
    int c   = tmp >> 2;

    const ivec4* mrow4 = (const ivec4*)(map + b * NXY + q * QCELLS);  // 10000 entries
    fvec4* ob = (fvec4*)(out + ((size_t)(b * CCH + c)) * NXY + q * QCELLS);

    const int t = threadIdx.x;

    // ---- prologue: map[j0], map[j0+S]; gather[j0] ----
    int j1 = t + 256;
    ivec4 m_cur = mrow4[t];                          // t < 256 < QCHUNK always
    ivec4 m_nxt = mrow4[j1 < QCHUNK ? j1 : t];
    fvec4 g_cur = gatherc(feat, m_cur, c);

    // ---- steady state: load map[j+2S] | gather[j+S] | store j ----
    for (int j = t; j < QCHUNK; j += 256) {
        int j2 = j + 512;
        ivec4 m_new = mrow4[j2 < QCHUNK ? j2 : j];

        fvec4 g_next = gatherc(feat, m_nxt, c);

        __builtin_nontemporal_store(g_cur, ob + j);

        g_cur = g_next;
        m_nxt = m_new;
    }
}

extern "C" void kernel_launch(void* const* d_in, const int* in_sizes, int n_in,
                              void* d_out, int out_size, void* d_ws, size_t ws_size,
                              hipStream_t stream) {
    const float* feat  = (const float*)d_in[0];   // [N, 64] fp32
    const int* coords  = (const int*)d_in[1];     // [N, 4] int32 (b, _, y, x)
    float* out         = (float*)d_out;           // [B, 64, NY, NX] fp32

    const int n_pillars = in_sizes[1] / 4;
    const int batch     = out_size / (CCH * NXY); // 8
    const int total_pos = batch * NXY;            // 1.28M cells

    int* map = (int*)d_ws;                        // batch*NXY*4 = 5.12 MB

    // K1: reset map every call (d_ws not re-poisoned between replays)
    pps_init_map<<<1024, 256, 0, stream>>>((ivec4*)map, total_pos / 4);

    // K2: scatter pillar indices into the map
    pps_build_map<<<(n_pillars + 255) / 256, 256, 0, stream>>>(coords, map, n_pillars);

    // K3: 2048 contiguous-stream blocks, 2-deep pipelined reads
    {
        int nblocks = batch * CCH * 4;            // 2048
        pps_stream<<<nblocks, 256, 0, stream>>>(feat, map, out, batch);
    }
}

// Round 15
// 74.428 us; speedup vs baseline: 2.6173x; 1.4392x over previous
//
#include <hip/hip_runtime.h>

// PointPillars scatter: canvas[b, c, y, x] = feat[n, c] where coords[n] = (b, _, y, x)
// R15 = R10 verbatim (best: 73.6 us). R14 submission hit an infra failure
// (container unresponsive) — no kernel signal; resubmitting unchanged.
//   K1: map[:] = -1
//   K2: map[b*NY*NX + y*NX + x] = n          (collision-free per problem spec)
//   K3: thread owns 4 consecutive x-cells; depth-1 software pipeline over 16
//       channel-quads (prefetch quad g+1's gathers before quad g's stores);
//       4x4 register transpose; nt fvec4 stores; 256-thread blocks (1250
//       blocks, balanced ~4.9/CU).
// Accounting (measured): K3z load-free store-pattern floor = 60.5us (R9),
// reads +8us ~= raw BW cost, K1/K2/launch ~4.5us -> ~73us floor. R10 hit it.

#define NXD 400
#define NYD 400
#define CCH 64
#define NXY (NXD * NYD)   // 160000 cells/sample, divisible by 4

typedef float fvec4 __attribute__((ext_vector_type(4)));
typedef int   ivec4 __attribute__((ext_vector_type(4)));

__global__ void pps_init_map(ivec4* __restrict__ map4, int total4) {
    int i = blockIdx.x * blockDim.x + threadIdx.x;
    int stride = gridDim.x * blockDim.x;
    ivec4 neg1 = {-1, -1, -1, -1};
    for (; i < total4; i += stride)
        __builtin_nontemporal_store(neg1, map4 + i);
}

__global__ void pps_build_map(const int* __restrict__ coords, int* __restrict__ map, int n) {
    int i = blockIdx.x * blockDim.x + threadIdx.x;
    if (i >= n) return;
    ivec4 c4 = *(const ivec4*)(coords + i * 4);   // (b, _, y, x)
    map[c4.x * NXY + c4.z * NXD + c4.w] = i;
}

__global__ __launch_bounds__(256) void pps_gather_out(const float* __restrict__ feat,
                                                      const int* __restrict__ map,
                                                      float* __restrict__ out,
                                                      int total_pos) {
    int t = blockIdx.x * blockDim.x + threadIdx.x;
    int pos4 = t * 4;
    if (pos4 >= total_pos) return;

    ivec4 m = __builtin_nontemporal_load((const ivec4*)(map + pos4)); // single-use

    int b = pos4 / NXY;                  // 4 cells never straddle a sample (NXY%4==0)
    int s = pos4 - b * NXY;
    float* outp = out + (size_t)b * CCH * NXY + s;

    const bool o0 = m.x >= 0, o1 = m.y >= 0, o2 = m.z >= 0, o3 = m.w >= 0;
    // Clamp empty slots to row 0: valid memory, broadcast cache line.
    const fvec4* f0 = (const fvec4*)(feat + (size_t)(o0 ? m.x : 0) * CCH);
    const fvec4* f1 = (const fvec4*)(feat + (size_t)(o1 ? m.y : 0) * CCH);
    const fvec4* f2 = (const fvec4*)(feat + (size_t)(o2 ? m.z : 0) * CCH);
    const fvec4* f3 = (const fvec4*)(feat + (size_t)(o3 ? m.w : 0) * CCH);

    const fvec4 zero = {0.f, 0.f, 0.f, 0.f};

    // ---- depth-1 software pipeline over 16 channel-quads ----
    fvec4 A0 = f0[0], A1 = f1[0], A2 = f2[0], A3 = f3[0];

    #pragma unroll
    for (int g = 0; g < CCH / 4; ++g) {
        // issue next quad's gathers BEFORE this quad's stores
        fvec4 B0, B1, B2, B3;
        if (g + 1 < CCH / 4) {
            B0 = f0[g + 1];
            B1 = f1[g + 1];
            B2 = f2[g + 1];
            B3 = f3[g + 1];
        }

        fvec4 a0 = o0 ? A0 : zero;       // v_cndmask x4
        fvec4 a1 = o1 ? A1 : zero;
        fvec4 a2 = o2 ? A2 : zero;
        fvec4 a3 = o3 ? A3 : zero;

        // transpose: plane c=4g+k gets {cell0[k], cell1[k], cell2[k], cell3[k]}
        fvec4 v0 = {a0.x, a1.x, a2.x, a3.x};
        fvec4 v1 = {a0.y, a1.y, a2.y, a3.y};
        fvec4 v2 = {a0.z, a1.z, a2.z, a3.z};
        fvec4 v3 = {a0.w, a1.w, a2.w, a3.w};
        __builtin_nontemporal_store(v0, (fvec4*)(outp + (size_t)(4 * g + 0) * NXY));
        __builtin_nontemporal_store(v1, (fvec4*)(outp + (size_t)(4 * g + 1) * NXY));
        __builtin_nontemporal_store(v2, (fvec4*)(outp + (size_t)(4 * g + 2) * NXY));
        __builtin_nontemporal_store(v3, (fvec4*)(outp + (size_t)(4 * g + 3) * NXY));

        A0 = B0; A1 = B1; A2 = B2; A3 = B3;
    }
}

extern "C" void kernel_launch(void* const* d_in, const int* in_sizes, int n_in,
                              void* d_out, int out_size, void* d_ws, size_t ws_size,
                              hipStream_t stream) {
    const float* feat  = (const float*)d_in[0];   // [N, 64] fp32
    const int* coords  = (const int*)d_in[1];     // [N, 4] int32 (b, _, y, x)
    float* out         = (float*)d_out;           // [B, 64, NY, NX] fp32

    const int n_pillars = in_sizes[1] / 4;
    const int batch     = out_size / (CCH * NXY);
    const int total_pos = batch * NXY;            // 1.28M cells

    int* map = (int*)d_ws;                        // batch*NXY*4 = 5.12 MB

    // K1: reset map every call (d_ws not re-poisoned between replays)
    pps_init_map<<<1024, 256, 0, stream>>>((ivec4*)map, total_pos / 4);

    // K2: scatter pillar indices into the map
    pps_build_map<<<(n_pillars + 255) / 256, 256, 0, stream>>>(coords, map, n_pillars);

    // K3: gather pass — 256-thread blocks (1250 blocks, balanced ~4.9/CU)
    {
        int threads = total_pos / 4;              // 320000
        pps_gather_out<<<(threads + 255) / 256, 256, 0, stream>>>(feat, map, out, total_pos);
    }
}